// Round 4
// baseline (459.792 us; speedup 1.0000x reference)
//
#include <hip/hip_runtime.h>

#define NTOK 98
#define DIM 192
#define HEADS 6
#define SCALE 0.17677669529663687f

using shortx8 = __attribute__((ext_vector_type(8))) short;
using floatx4 = __attribute__((ext_vector_type(4))) float;

static __device__ __forceinline__ unsigned short f2bf(float f) {
    unsigned u = __float_as_uint(f);
    u += 0x7FFFu + ((u >> 16) & 1u);   // RNE
    return (unsigned short)(u >> 16);
}

static __device__ __forceinline__ shortx8 pack8(const float* p, float scale) {
    float4 a = *(const float4*)p;
    float4 b = *(const float4*)(p + 4);
    shortx8 t;
    t[0] = (short)f2bf(a.x * scale); t[1] = (short)f2bf(a.y * scale);
    t[2] = (short)f2bf(a.z * scale); t[3] = (short)f2bf(a.w * scale);
    t[4] = (short)f2bf(b.x * scale); t[5] = (short)f2bf(b.y * scale);
    t[6] = (short)f2bf(b.z * scale); t[7] = (short)f2bf(b.w * scale);
    return t;
}

static __device__ __forceinline__ shortx8 frag_from_words(unsigned w0, unsigned w1,
                                                          unsigned w2, unsigned w3) {
    union { unsigned u[4]; shortx8 s; } t;
    t.u[0] = w0; t.u[1] = w1; t.u[2] = w2; t.u[3] = w3;
    return t.s;
}

// quad-exchange: build B/A-frag word set from packed pairs held by the 4 lanes sharing l15.
// target (quad, jj): src lane = 32*(quad&1) + (jj>=4)*16 + l15; word = pk[.][jj&3>>1];
// tile select lo/hi by (quad&2). Verified element-wise for both P->PV and O->proj.
template <bool HI>
static __device__ __forceinline__ shortx8 xchg4(unsigned lo0, unsigned lo1,
                                                unsigned hi0, unsigned hi1,
                                                int A0b, int A1b, bool hiSel) {
    unsigned l0 = (unsigned)__builtin_amdgcn_ds_bpermute(A0b, (int)lo0);
    unsigned l1 = (unsigned)__builtin_amdgcn_ds_bpermute(A0b, (int)lo1);
    unsigned l2 = (unsigned)__builtin_amdgcn_ds_bpermute(A1b, (int)lo0);
    unsigned l3 = (unsigned)__builtin_amdgcn_ds_bpermute(A1b, (int)lo1);
    unsigned h0 = 0, h1 = 0, h2 = 0, h3 = 0;
    if (HI) {
        h0 = (unsigned)__builtin_amdgcn_ds_bpermute(A0b, (int)hi0);
        h1 = (unsigned)__builtin_amdgcn_ds_bpermute(A0b, (int)hi1);
        h2 = (unsigned)__builtin_amdgcn_ds_bpermute(A1b, (int)hi0);
        h3 = (unsigned)__builtin_amdgcn_ds_bpermute(A1b, (int)hi1);
    }
    return frag_from_words(hiSel ? h0 : l0, hiSel ? h1 : l1,
                           hiSel ? h2 : l2, hiSel ? h3 : l3);
}

// ---------------- prep: transposed bias/mask tables + weight bf16 fragment layouts --------
// biasT[h][j][i] = rpb[relidx[i*98+j]*6+h]   (bias[h][i][j] transposed for swapped-QK C-init)
// maskT[w][j][i] = mask[w][i][j]
// kvB[((ks*24+NT)*64+lane)*8+jj] = kv_w[(ks*32+quad*8+jj)*384 + NT*16+(lane&15)]
// pB [((ks*12+NT)*64+lane)*8+jj] = proj_w[(ks*32+quad*8+jj)*192 + NT*16+(lane&15)]
__global__ void prep_kernel(const float* __restrict__ rpb, const int* __restrict__ relidx,
                            const float* __restrict__ mask,
                            const float* __restrict__ kvw, const float* __restrict__ pw,
                            float* __restrict__ biasT, float* __restrict__ maskT,
                            unsigned short* __restrict__ kvB, unsigned short* __restrict__ pB) {
    int e = blockIdx.x * 256 + threadIdx.x;
    if (e < HEADS * NTOK * NTOK) {
        int h = e / (NTOK * NTOK), rem = e % (NTOK * NTOK);
        int j = rem / NTOK, i = rem % NTOK;
        biasT[e] = rpb[relidx[i * NTOK + j] * HEADS + h];
    }
    if (e < 64 * NTOK * NTOK) {
        int wd = e / (NTOK * NTOK), rem = e % (NTOK * NTOK);
        int j = rem / NTOK, i = rem % NTOK;
        maskT[e] = mask[((size_t)wd * NTOK + i) * NTOK + j];
    }
    if (e < 73728) {
        int jj = e & 7, lane = (e >> 3) & 63, t = e >> 9;
        int NT = t % 24, ks = t / 24;
        int c = ks * 32 + (lane >> 4) * 8 + jj;
        int n = NT * 16 + (lane & 15);
        kvB[e] = f2bf(kvw[c * 384 + n]);
    }
    if (e < 36864) {
        int jj = e & 7, lane = (e >> 3) & 63, t = e >> 9;
        int NT = t % 12, ks = t / 12;
        int c = ks * 32 + (lane >> 4) * 8 + jj;
        int n = NT * 16 + (lane & 15);
        pB[e] = f2bf(pw[c * 192 + n]);
    }
}

// ---------------- fused: swapped-QK attention (no P/O LDS) + proj, one block/window -------
// LDS: kB3 [3][7][64][8]  (21504 B)  k frags for current head-group (A-frag for swapped QK)
//      vB3 [3][2][4][64][8] (24576 B) v frags (A-frag for swapped PV)
// Total 46080 B -> 3 blocks/CU (21 waves). Head phase has NO LDS writes, NO barriers.
__global__ __launch_bounds__(448, 3) void fused_kernel(
    const float* __restrict__ skip, const float* __restrict__ xup,
    const float* __restrict__ kv_b,
    const float* __restrict__ biasT, const float* __restrict__ maskT,
    const unsigned short* __restrict__ kvB,
    const unsigned short* __restrict__ pB, const float* __restrict__ pb,
    float* __restrict__ out) {

    __shared__ __align__(16) unsigned short kB3[3 * 7 * 512];
    __shared__ __align__(16) unsigned short vB3[3 * 2 * 4 * 512];

    const int tid  = threadIdx.x;
    const int w    = tid >> 6;        // wave id = mtile (i-range w*16..w*16+15)
    const int lane = tid & 63;
    const int l15  = lane & 15;
    const int quad = lane >> 4;
    const int win  = blockIdx.x;

    // zero v pad slab (tokens 96..127 region; real 96,97 overwritten by staging after barrier)
    for (int e = tid; e < 6 * 512; e += 448)
        vB3[(e / 512) * 2048 + 3 * 512 + (e & 511)] = 0;
    __syncthreads();

    const int mA  = w * 16 + l15;          // this lane's i (token)
    const int mAc = mA < NTOK ? mA : 97;   // clamp pad rows (finite, discarded later)

    // bpermute addresses for quad-exchange (bytes): lane 32*(quad&1)+l15 and +16
    const int A0b = ((32 * (quad & 1) + l15) << 2);
    const int A1b = A0b + 64;

    unsigned opk[12][2];   // O^T packed bf16: [h*2+ntv][word], lane holds col i=l15

    #pragma unroll
    for (int g = 0; g < 2; ++g) {
        if (g) __syncthreads();   // group-0 PV reads done before re-stage

        // ---- stage k,v for heads 3g..3g+2 (afr live only inside this scope) ----
        {
            shortx8 afr[6];
            const float* sr = skip + ((size_t)win * NTOK + mAc) * DIM + quad * 8;
            #pragma unroll
            for (int ks = 0; ks < 6; ++ks) afr[ks] = pack8(sr + ks * 32, 1.0f);
            #pragma unroll
            for (int nt = 0; nt < 12; ++nt) {
                const int NTg = (nt < 6) ? (6 * g + nt) : (6 + 6 * g + nt);
                const float cb = kv_b[NTg * 16 + l15];
                floatx4 acc = {cb, cb, cb, cb};
                #pragma unroll
                for (int ks = 0; ks < 6; ++ks) {
                    shortx8 bf = *(const shortx8*)(kvB + ((size_t)((ks * 24 + NTg) * 64 + lane)) * 8);
                    acc = __builtin_amdgcn_mfma_f32_16x16x32_bf16(afr[ks], bf, acc, 0, 0, 0);
                }
                if (nt < 6) {  // k -> kB3: lane holds k[j=jt*16+l15][dh=quad*8+jj]
                    const int ch = nt * 16 + l15, hh = ch >> 5, dh = ch & 31;
                    const int base = ((hh * 7 + w) * 64) * 8 + (dh & 7);
                    const int lphi = ((dh >> 3) & 3) << 4;
                    #pragma unroll
                    for (int r = 0; r < 4; ++r) {
                        int mm = quad * 4 + r;   // pad rows written too: finite row-97 copies
                        kB3[base + (mm | lphi) * 8] = f2bf(acc[r]);
                    }
                } else {       // v -> vB3: lane holds v[j=ks*32+quad*8+jj][dh=l15 (+16*ntv)]
                    const int cv = (nt - 6) * 16 + l15, hh = cv >> 5, dh = cv & 31, ntv = dh >> 4;
                    #pragma unroll
                    for (int r = 0; r < 4; ++r) {
                        int m = w * 16 + quad * 4 + r;
                        if (m < NTOK) {
                            int lp = (dh & 15) | (((m >> 3) & 3) << 4);
                            vB3[(((hh * 2 + ntv) * 4 + (m >> 5)) * 64 + lp) * 8 + (m & 7)] = f2bf(acc[r]);
                        }
                    }
                }
            }
        }
        __syncthreads();   // kB3/vB3 visible

        // ---- 3 heads: swapped QK + per-lane softmax + PV via quad-exchange ----
        #pragma unroll
        for (int hp = 0; hp < 3; ++hp) {
            const int h = 3 * g + hp;
            // q B-frag (scaled): lane holds q[i=l15-based][d=quad*8+jj]
            shortx8 qf = pack8(xup + ((size_t)win * NTOK + mAc) * DIM + h * 32 + quad * 8, SCALE);

            // C-init: S'[j][i] = bias[h][i][j] + mask[win][i][j], from transposed tables
            floatx4 S[7];
            {
                const float* bT = biasT + (size_t)h * (NTOK * NTOK);
                const float* mT = maskT + (size_t)(win & 63) * (NTOK * NTOK);
                #pragma unroll
                for (int nt = 0; nt < 7; ++nt) {
                    #pragma unroll
                    for (int r = 0; r < 4; ++r) {
                        int j = nt * 16 + quad * 4 + r;
                        S[nt][r] = (j < NTOK) ? (bT[j * NTOK + mAc] + mT[j * NTOK + mAc])
                                              : -1e30f;
                    }
                }
            }
            // swapped QK: S' = K·Qᵀ -> lane: col i=l15, rows j=nt*16+quad*4+r
            #pragma unroll
            for (int nt = 0; nt < 7; ++nt) {
                shortx8 bk = *(const shortx8*)&kB3[((hp * 7 + nt) * 64 + lane) * 8];
                S[nt] = __builtin_amdgcn_mfma_f32_16x16x32_bf16(bk, qf, S[nt], 0, 0, 0);
            }
            // softmax over row i=l15: 28 in-lane values + cross-quad reduce (xor 16, 32)
            float mx;
            {
                float m0 = fmaxf(fmaxf(S[0][0], S[0][1]), fmaxf(S[0][2], S[0][3]));
                float m1 = fmaxf(fmaxf(S[1][0], S[1][1]), fmaxf(S[1][2], S[1][3]));
                float m2 = fmaxf(fmaxf(S[2][0], S[2][1]), fmaxf(S[2][2], S[2][3]));
                float m3 = fmaxf(fmaxf(S[3][0], S[3][1]), fmaxf(S[3][2], S[3][3]));
                float m4 = fmaxf(fmaxf(S[4][0], S[4][1]), fmaxf(S[4][2], S[4][3]));
                float m5 = fmaxf(fmaxf(S[5][0], S[5][1]), fmaxf(S[5][2], S[5][3]));
                float m6 = fmaxf(fmaxf(S[6][0], S[6][1]), fmaxf(S[6][2], S[6][3]));
                mx = fmaxf(fmaxf(fmaxf(m0, m1), fmaxf(m2, m3)), fmaxf(fmaxf(m4, m5), m6));
                mx = fmaxf(mx, __shfl_xor(mx, 16));
                mx = fmaxf(mx, __shfl_xor(mx, 32));
            }
            float sm = 0.f;
            #pragma unroll
            for (int nt = 0; nt < 7; ++nt) {
                #pragma unroll
                for (int r = 0; r < 4; ++r) { S[nt][r] = __expf(S[nt][r] - mx); }
                sm += (S[nt][0] + S[nt][1]) + (S[nt][2] + S[nt][3]);
            }
            sm += __shfl_xor(sm, 16);
            sm += __shfl_xor(sm, 32);
            const float inv = 1.0f / sm;   // per-lane (row i=l15); folded into PV epilogue

            // pack P rows (unnormalized, <=1) as bf16 pairs
            unsigned pk[7][2];
            #pragma unroll
            for (int nt = 0; nt < 7; ++nt) {
                pk[nt][0] = (unsigned)f2bf(S[nt][0]) | ((unsigned)f2bf(S[nt][1]) << 16);
                pk[nt][1] = (unsigned)f2bf(S[nt][2]) | ((unsigned)f2bf(S[nt][3]) << 16);
            }
            // PV: O^T[dh][i] += Vᵀ · P'  (A=vB3 frag, B=P' via quad-exchange)
            floatx4 o0 = {0.f, 0.f, 0.f, 0.f}, o1 = {0.f, 0.f, 0.f, 0.f};
            const bool hiSel = (quad & 2) != 0;
            #pragma unroll
            for (int ks = 0; ks < 4; ++ks) {
                shortx8 pfr;
                if (ks < 3)
                    pfr = xchg4<true>(pk[2 * ks][0], pk[2 * ks][1],
                                      pk[2 * ks + 1][0], pk[2 * ks + 1][1], A0b, A1b, hiSel);
                else   // j-tile 7 is pad -> zeros for quad>=2
                    pfr = xchg4<false>(pk[6][0], pk[6][1], 0u, 0u, A0b, A1b, hiSel);
                shortx8 vb0 = *(const shortx8*)&vB3[(((hp * 2 + 0) * 4 + ks) * 64 + lane) * 8];
                o0 = __builtin_amdgcn_mfma_f32_16x16x32_bf16(vb0, pfr, o0, 0, 0, 0);
                shortx8 vb1 = *(const shortx8*)&vB3[(((hp * 2 + 1) * 4 + ks) * 64 + lane) * 8];
                o1 = __builtin_amdgcn_mfma_f32_16x16x32_bf16(vb1, pfr, o1, 0, 0, 0);
            }
            opk[h * 2 + 0][0] = (unsigned)f2bf(o0[0] * inv) | ((unsigned)f2bf(o0[1] * inv) << 16);
            opk[h * 2 + 0][1] = (unsigned)f2bf(o0[2] * inv) | ((unsigned)f2bf(o0[3] * inv) << 16);
            opk[h * 2 + 1][0] = (unsigned)f2bf(o1[0] * inv) | ((unsigned)f2bf(o1[1] * inv) << 16);
            opk[h * 2 + 1][1] = (unsigned)f2bf(o1[2] * inv) | ((unsigned)f2bf(o1[3] * inv) << 16);
        }
    }

    // ---- proj: O A-frags via the same quad-exchange (no LDS, no barrier) ----
    const bool hiSel = (quad & 2) != 0;
    shortx8 oa[6];
    #pragma unroll
    for (int hh = 0; hh < 6; ++hh)
        oa[hh] = xchg4<true>(opk[hh * 2][0], opk[hh * 2][1],
                             opk[hh * 2 + 1][0], opk[hh * 2 + 1][1], A0b, A1b, hiSel);
    float* obase = out + (size_t)win * NTOK * DIM;
    #pragma unroll
    for (int nt = 0; nt < 12; ++nt) {
        const int n = nt * 16 + l15;
        const float bb = pb[n];
        floatx4 acc = {bb, bb, bb, bb};
        #pragma unroll
        for (int ks = 0; ks < 6; ++ks) {
            shortx8 bf = *(const shortx8*)(pB + ((size_t)((ks * 12 + nt) * 64 + lane)) * 8);
            acc = __builtin_amdgcn_mfma_f32_16x16x32_bf16(oa[ks], bf, acc, 0, 0, 0);
        }
        #pragma unroll
        for (int r = 0; r < 4; ++r) {
            int m = w * 16 + quad * 4 + r;
            if (m < NTOK) obase[m * DIM + n] = acc[r];
        }
    }
}

extern "C" void kernel_launch(void* const* d_in, const int* in_sizes, int n_in,
                              void* d_out, int out_size, void* d_ws, size_t ws_size,
                              hipStream_t stream) {
    const float* skip   = (const float*)d_in[0];
    const float* x_up   = (const float*)d_in[1];
    const float* mask   = (const float*)d_in[2];
    const float* kv_w   = (const float*)d_in[3];
    const float* kv_b   = (const float*)d_in[4];
    const float* proj_w = (const float*)d_in[5];
    const float* proj_b = (const float*)d_in[6];
    const float* rpb    = (const float*)d_in[7];
    const int*   relidx = (const int*)d_in[8];
    float* out = (float*)d_out;

    float*          biasT = (float*)d_ws;                                 //   230,496 B
    float*          maskT = (float*)((char*)d_ws + 230496);               // 2,458,624 B
    unsigned short* kvB   = (unsigned short*)((char*)d_ws + 2689120);     //   147,456 B
    unsigned short* pB    = (unsigned short*)((char*)d_ws + 2836576);     //    73,728 B

    prep_kernel<<<2402, 256, 0, stream>>>(rpb, relidx, mask, kv_w, proj_w,
                                          biasT, maskT, kvB, pB);
    fused_kernel<<<1024, 448, 0, stream>>>(skip, x_up, kv_b, biasT, maskT, kvB, pB,
                                           proj_b, out);
}

// Round 5
// 385.183 us; speedup vs baseline: 1.1937x; 1.1937x over previous
//
#include <hip/hip_runtime.h>

#define NTOK 98
#define DIM 192
#define HEADS 6
#define SCALE 0.17677669529663687f

using shortx8 = __attribute__((ext_vector_type(8))) short;
using floatx4 = __attribute__((ext_vector_type(4))) float;

static __device__ __forceinline__ unsigned short f2bf(float f) {
    unsigned u = __float_as_uint(f);
    u += 0x7FFFu + ((u >> 16) & 1u);   // RNE
    return (unsigned short)(u >> 16);
}

static __device__ __forceinline__ shortx8 pack8(const float* p, float scale) {
    float4 a = *(const float4*)p;
    float4 b = *(const float4*)(p + 4);
    shortx8 t;
    t[0] = (short)f2bf(a.x * scale); t[1] = (short)f2bf(a.y * scale);
    t[2] = (short)f2bf(a.z * scale); t[3] = (short)f2bf(a.w * scale);
    t[4] = (short)f2bf(b.x * scale); t[5] = (short)f2bf(b.y * scale);
    t[6] = (short)f2bf(b.z * scale); t[7] = (short)f2bf(b.w * scale);
    return t;
}

static __device__ __forceinline__ shortx8 frag_from_words(unsigned w0, unsigned w1,
                                                          unsigned w2, unsigned w3) {
    union { unsigned u[4]; shortx8 s; } t;
    t.u[0] = w0; t.u[1] = w1; t.u[2] = w2; t.u[3] = w3;
    return t.s;
}

// quad-exchange (validated r4): build frag words from the 4 lanes sharing l15.
template <bool HI>
static __device__ __forceinline__ shortx8 xchg4(unsigned lo0, unsigned lo1,
                                                unsigned hi0, unsigned hi1,
                                                int A0b, int A1b, bool hiSel) {
    unsigned l0 = (unsigned)__builtin_amdgcn_ds_bpermute(A0b, (int)lo0);
    unsigned l1 = (unsigned)__builtin_amdgcn_ds_bpermute(A0b, (int)lo1);
    unsigned l2 = (unsigned)__builtin_amdgcn_ds_bpermute(A1b, (int)lo0);
    unsigned l3 = (unsigned)__builtin_amdgcn_ds_bpermute(A1b, (int)lo1);
    unsigned h0 = 0, h1 = 0, h2 = 0, h3 = 0;
    if (HI) {
        h0 = (unsigned)__builtin_amdgcn_ds_bpermute(A0b, (int)hi0);
        h1 = (unsigned)__builtin_amdgcn_ds_bpermute(A0b, (int)hi1);
        h2 = (unsigned)__builtin_amdgcn_ds_bpermute(A1b, (int)hi0);
        h3 = (unsigned)__builtin_amdgcn_ds_bpermute(A1b, (int)hi1);
    }
    return frag_from_words(hiSel ? h0 : l0, hiSel ? h1 : l1,
                           hiSel ? h2 : l2, hiSel ? h3 : l3);
}

// ---------------- prep: transposed bias/mask tables + weight bf16 fragment layouts --------
__global__ void prep_kernel(const float* __restrict__ rpb, const int* __restrict__ relidx,
                            const float* __restrict__ mask,
                            const float* __restrict__ kvw, const float* __restrict__ pw,
                            float* __restrict__ biasT, float* __restrict__ maskT,
                            unsigned short* __restrict__ kvB, unsigned short* __restrict__ pB) {
    int e = blockIdx.x * 256 + threadIdx.x;
    if (e < HEADS * NTOK * NTOK) {
        int h = e / (NTOK * NTOK), rem = e % (NTOK * NTOK);
        int j = rem / NTOK, i = rem % NTOK;
        biasT[e] = rpb[relidx[i * NTOK + j] * HEADS + h];
    }
    if (e < 64 * NTOK * NTOK) {
        int wd = e / (NTOK * NTOK), rem = e % (NTOK * NTOK);
        int j = rem / NTOK, i = rem % NTOK;
        maskT[e] = mask[((size_t)wd * NTOK + i) * NTOK + j];
    }
    if (e < 73728) {
        int jj = e & 7, lane = (e >> 3) & 63, t = e >> 9;
        int NT = t % 24, ks = t / 24;
        int c = ks * 32 + (lane >> 4) * 8 + jj;
        int n = NT * 16 + (lane & 15);
        kvB[e] = f2bf(kvw[c * 384 + n]);
    }
    if (e < 36864) {
        int jj = e & 7, lane = (e >> 3) & 63, t = e >> 9;
        int NT = t % 12, ks = t / 12;
        int c = ks * 32 + (lane >> 4) * 8 + jj;
        int n = NT * 16 + (lane & 15);
        pB[e] = f2bf(pw[c * 192 + n]);
    }
}

// ---------------- attn: swapped-QK, per (window, head-triple); O -> out (f32) -------------
// LDS: kB3 21504 B + vB3 24576 B = 46080 -> 3 blocks/CU; (448,3) -> 85-reg cap, 21 waves/CU.
// No P/O LDS, no per-head barriers (P and O move via quad-exchange / registers).
__global__ __launch_bounds__(448, 3) void attn_kernel(
    const float* __restrict__ skip, const float* __restrict__ xup,
    const float* __restrict__ kv_b,
    const float* __restrict__ biasT, const float* __restrict__ maskT,
    const unsigned short* __restrict__ kvB,
    float* __restrict__ out) {

    __shared__ __align__(16) unsigned short kB3[3 * 7 * 512];
    __shared__ __align__(16) unsigned short vB3[3 * 2 * 4 * 512];

    const int tid  = threadIdx.x;
    const int w    = tid >> 6;        // wave id = i-tile
    const int lane = tid & 63;
    const int l15  = lane & 15;
    const int quad = lane >> 4;
    const int win  = blockIdx.x >> 1;
    const int g    = blockIdx.x & 1;  // head triple: 3g..3g+2

    // zero v pad slab (j tokens 96..127 region; real 96,97 re-written by staging)
    for (int e = tid; e < 6 * 512; e += 448)
        vB3[(e / 512) * 2048 + 3 * 512 + (e & 511)] = 0;
    __syncthreads();

    const int mA  = w * 16 + l15;          // this lane's i (token)
    const int mAc = mA < NTOK ? mA : 97;   // clamp pad rows (finite, discarded)

    const int A0b = ((32 * (quad & 1) + l15) << 2);   // bpermute byte addrs
    const int A1b = A0b + 64;

    // ---- stage k,v for heads 3g..3g+2 ----
    {
        shortx8 afr[6];
        const float* sr = skip + ((size_t)win * NTOK + mAc) * DIM + quad * 8;
        #pragma unroll
        for (int ks = 0; ks < 6; ++ks) afr[ks] = pack8(sr + ks * 32, 1.0f);
        #pragma unroll
        for (int nt = 0; nt < 12; ++nt) {
            const int NTg = (nt < 6) ? (6 * g + nt) : (6 + 6 * g + nt);
            const float cb = kv_b[NTg * 16 + l15];
            floatx4 acc = {cb, cb, cb, cb};
            #pragma unroll
            for (int ks = 0; ks < 6; ++ks) {
                shortx8 bf = *(const shortx8*)(kvB + ((size_t)((ks * 24 + NTg) * 64 + lane)) * 8);
                acc = __builtin_amdgcn_mfma_f32_16x16x32_bf16(afr[ks], bf, acc, 0, 0, 0);
            }
            if (nt < 6) {  // k -> kB3 (A-frag for swapped QK)
                const int ch = nt * 16 + l15, hh = ch >> 5, dh = ch & 31;
                const int base = ((hh * 7 + w) * 64) * 8 + (dh & 7);
                const int lphi = ((dh >> 3) & 3) << 4;
                #pragma unroll
                for (int r = 0; r < 4; ++r) {
                    int mm = quad * 4 + r;   // pad rows written too: finite row-97 copies
                    kB3[base + (mm | lphi) * 8] = f2bf(acc[r]);
                }
            } else {       // v -> vB3 (A-frag for swapped PV)
                const int cv = (nt - 6) * 16 + l15, hh = cv >> 5, dh = cv & 31, ntv = dh >> 4;
                #pragma unroll
                for (int r = 0; r < 4; ++r) {
                    int m = w * 16 + quad * 4 + r;
                    if (m < NTOK) {
                        int lp = (dh & 15) | (((m >> 3) & 3) << 4);
                        vB3[(((hh * 2 + ntv) * 4 + (m >> 5)) * 64 + lp) * 8 + (m & 7)] = f2bf(acc[r]);
                    }
                }
            }
        }
    }
    __syncthreads();   // kB3/vB3 visible — the only barrier pair in the kernel

    // ---- 3 heads: swapped QK + per-lane softmax + PV via quad-exchange ----
    #pragma unroll
    for (int hp = 0; hp < 3; ++hp) {
        const int h = 3 * g + hp;
        shortx8 qf = pack8(xup + ((size_t)win * NTOK + mAc) * DIM + h * 32 + quad * 8, SCALE);

        // C-init: S'[j][i] = bias[h][i][j] + mask[win][i][j] (transposed tables)
        floatx4 S[7];
        {
            const float* bT = biasT + (size_t)h * (NTOK * NTOK);
            const float* mT = maskT + (size_t)(win & 63) * (NTOK * NTOK);
            #pragma unroll
            for (int nt = 0; nt < 7; ++nt) {
                #pragma unroll
                for (int r = 0; r < 4; ++r) {
                    int j = nt * 16 + quad * 4 + r;
                    S[nt][r] = (j < NTOK) ? (bT[j * NTOK + mAc] + mT[j * NTOK + mAc])
                                          : -1e30f;
                }
            }
        }
        // swapped QK: S' = K·Qᵀ (lane: col i=l15, rows j=nt*16+quad*4+r)
        #pragma unroll
        for (int nt = 0; nt < 7; ++nt) {
            shortx8 bk = *(const shortx8*)&kB3[((hp * 7 + nt) * 64 + lane) * 8];
            S[nt] = __builtin_amdgcn_mfma_f32_16x16x32_bf16(bk, qf, S[nt], 0, 0, 0);
        }
        // softmax over row i=l15: 28 in-lane + cross-quad reduce (xor 16, 32)
        float mx;
        {
            float m0 = fmaxf(fmaxf(S[0][0], S[0][1]), fmaxf(S[0][2], S[0][3]));
            float m1 = fmaxf(fmaxf(S[1][0], S[1][1]), fmaxf(S[1][2], S[1][3]));
            float m2 = fmaxf(fmaxf(S[2][0], S[2][1]), fmaxf(S[2][2], S[2][3]));
            float m3 = fmaxf(fmaxf(S[3][0], S[3][1]), fmaxf(S[3][2], S[3][3]));
            float m4 = fmaxf(fmaxf(S[4][0], S[4][1]), fmaxf(S[4][2], S[4][3]));
            float m5 = fmaxf(fmaxf(S[5][0], S[5][1]), fmaxf(S[5][2], S[5][3]));
            float m6 = fmaxf(fmaxf(S[6][0], S[6][1]), fmaxf(S[6][2], S[6][3]));
            mx = fmaxf(fmaxf(fmaxf(m0, m1), fmaxf(m2, m3)), fmaxf(fmaxf(m4, m5), m6));
            mx = fmaxf(mx, __shfl_xor(mx, 16));
            mx = fmaxf(mx, __shfl_xor(mx, 32));
        }
        float sm = 0.f;
        #pragma unroll
        for (int nt = 0; nt < 7; ++nt) {
            #pragma unroll
            for (int r = 0; r < 4; ++r) { S[nt][r] = __expf(S[nt][r] - mx); }
            sm += (S[nt][0] + S[nt][1]) + (S[nt][2] + S[nt][3]);
        }
        sm += __shfl_xor(sm, 16);
        sm += __shfl_xor(sm, 32);
        const float inv = 1.0f / sm;   // per-lane (row i=l15)

        // pack P rows (unnormalized) as bf16 pairs
        unsigned pk[7][2];
        #pragma unroll
        for (int nt = 0; nt < 7; ++nt) {
            pk[nt][0] = (unsigned)f2bf(S[nt][0]) | ((unsigned)f2bf(S[nt][1]) << 16);
            pk[nt][1] = (unsigned)f2bf(S[nt][2]) | ((unsigned)f2bf(S[nt][3]) << 16);
        }
        // PV: O^T[dh][i] += Vᵀ·P' (A=vB3 frag, B=P' via quad-exchange)
        floatx4 o0 = {0.f, 0.f, 0.f, 0.f}, o1 = {0.f, 0.f, 0.f, 0.f};
        const bool hiSel = (quad & 2) != 0;
        #pragma unroll
        for (int ks = 0; ks < 4; ++ks) {
            shortx8 pfr;
            if (ks < 3)
                pfr = xchg4<true>(pk[2 * ks][0], pk[2 * ks][1],
                                  pk[2 * ks + 1][0], pk[2 * ks + 1][1], A0b, A1b, hiSel);
            else
                pfr = xchg4<false>(pk[6][0], pk[6][1], 0u, 0u, A0b, A1b, hiSel);
            shortx8 vb0 = *(const shortx8*)&vB3[(((hp * 2 + 0) * 4 + ks) * 64 + lane) * 8];
            o0 = __builtin_amdgcn_mfma_f32_16x16x32_bf16(vb0, pfr, o0, 0, 0, 0);
            shortx8 vb1 = *(const shortx8*)&vB3[(((hp * 2 + 1) * 4 + ks) * 64 + lane) * 8];
            o1 = __builtin_amdgcn_mfma_f32_16x16x32_bf16(vb1, pfr, o1, 0, 0, 0);
        }
        // O store (normalized f32): lane holds col i=l15, rows dh=quad*4+r per ntv tile
        if (mA < NTOK) {
            float* orow = out + ((size_t)win * NTOK + mA) * DIM + h * 32;
            #pragma unroll
            for (int r = 0; r < 4; ++r) {
                orow[quad * 4 + r]      = o0[r] * inv;
                orow[16 + quad * 4 + r] = o1[r] * inv;
            }
        }
    }
}

// ---------------- proj: in-place out = O @ proj_w + proj_b, one wave per (win, mtile) -----
// grid 3584 x 128 (2 waves/block); (128,12) -> 85-reg cap, ~24 waves/CU resident.
// In-place safe: each wave reads only its own mtile's rows (regs) before storing them.
__global__ __launch_bounds__(128, 12) void proj_kernel(
    float* __restrict__ io, const unsigned short* __restrict__ pB,
    const float* __restrict__ pb) {
    const int tid  = threadIdx.x;
    const int lane = tid & 63;
    const int l15  = lane & 15;
    const int quad = lane >> 4;
    const int idx  = blockIdx.x * 2 + (tid >> 6);   // (win*7 + mt), 0..7167
    const int win  = idx / 7;
    const int mt   = idx - win * 7;

    float* base = io + (size_t)win * NTOK * DIM;
    const int mA  = mt * 16 + l15;
    const int mAc = mA < NTOK ? mA : 97;

    shortx8 afr[6];
    {
        const float* ar = base + mAc * DIM + quad * 8;
        #pragma unroll
        for (int ks = 0; ks < 6; ++ks) afr[ks] = pack8(ar + ks * 32, 1.0f);
    }
    #pragma unroll
    for (int nt = 0; nt < 12; ++nt) {
        const int n = nt * 16 + l15;
        const float bb = pb[n];
        floatx4 acc = {bb, bb, bb, bb};
        #pragma unroll
        for (int ks = 0; ks < 6; ++ks) {
            shortx8 bf = *(const shortx8*)(pB + ((size_t)((ks * 12 + nt) * 64 + lane)) * 8);
            acc = __builtin_amdgcn_mfma_f32_16x16x32_bf16(afr[ks], bf, acc, 0, 0, 0);
        }
        #pragma unroll
        for (int r = 0; r < 4; ++r) {
            int m = mt * 16 + quad * 4 + r;
            if (m < NTOK) base[m * DIM + n] = acc[r];
        }
    }
}

extern "C" void kernel_launch(void* const* d_in, const int* in_sizes, int n_in,
                              void* d_out, int out_size, void* d_ws, size_t ws_size,
                              hipStream_t stream) {
    const float* skip   = (const float*)d_in[0];
    const float* x_up   = (const float*)d_in[1];
    const float* mask   = (const float*)d_in[2];
    const float* kv_w   = (const float*)d_in[3];
    const float* kv_b   = (const float*)d_in[4];
    const float* proj_w = (const float*)d_in[5];
    const float* proj_b = (const float*)d_in[6];
    const float* rpb    = (const float*)d_in[7];
    const int*   relidx = (const int*)d_in[8];
    float* out = (float*)d_out;

    float*          biasT = (float*)d_ws;                                 //   230,496 B
    float*          maskT = (float*)((char*)d_ws + 230496);               // 2,458,624 B
    unsigned short* kvB   = (unsigned short*)((char*)d_ws + 2689120);     //   147,456 B
    unsigned short* pB    = (unsigned short*)((char*)d_ws + 2836576);     //    73,728 B

    prep_kernel<<<2402, 256, 0, stream>>>(rpb, relidx, mask, kv_w, proj_w,
                                          biasT, maskT, kvB, pB);
    attn_kernel<<<2048, 448, 0, stream>>>(skip, x_up, kv_b, biasT, maskT, kvB, out);
    proj_kernel<<<3584, 128, 0, stream>>>(out, pB, proj_b);
}

// Round 6
// 362.260 us; speedup vs baseline: 1.2692x; 1.0633x over previous
//
#include <hip/hip_runtime.h>

#define NTOK 98
#define DIM 192
#define HEADS 6
#define SCALE 0.17677669529663687f

using shortx8 = __attribute__((ext_vector_type(8))) short;
using floatx4 = __attribute__((ext_vector_type(4))) float;

static __device__ __forceinline__ unsigned short f2bf(float f) {
    unsigned u = __float_as_uint(f);
    u += 0x7FFFu + ((u >> 16) & 1u);   // RNE
    return (unsigned short)(u >> 16);
}

static __device__ __forceinline__ shortx8 pack8(const float* p, float scale) {
    float4 a = *(const float4*)p;
    float4 b = *(const float4*)(p + 4);
    shortx8 t;
    t[0] = (short)f2bf(a.x * scale); t[1] = (short)f2bf(a.y * scale);
    t[2] = (short)f2bf(a.z * scale); t[3] = (short)f2bf(a.w * scale);
    t[4] = (short)f2bf(b.x * scale); t[5] = (short)f2bf(b.y * scale);
    t[6] = (short)f2bf(b.z * scale); t[7] = (short)f2bf(b.w * scale);
    return t;
}

static __device__ __forceinline__ shortx8 frag_from_words(unsigned w0, unsigned w1,
                                                          unsigned w2, unsigned w3) {
    union { unsigned u[4]; shortx8 s; } t;
    t.u[0] = w0; t.u[1] = w1; t.u[2] = w2; t.u[3] = w3;
    return t.s;
}

// quad-exchange (validated r4/r5): build frag words from the 4 lanes sharing l15.
template <bool HI>
static __device__ __forceinline__ shortx8 xchg4(unsigned lo0, unsigned lo1,
                                                unsigned hi0, unsigned hi1,
                                                int A0b, int A1b, bool hiSel) {
    unsigned l0 = (unsigned)__builtin_amdgcn_ds_bpermute(A0b, (int)lo0);
    unsigned l1 = (unsigned)__builtin_amdgcn_ds_bpermute(A0b, (int)lo1);
    unsigned l2 = (unsigned)__builtin_amdgcn_ds_bpermute(A1b, (int)lo0);
    unsigned l3 = (unsigned)__builtin_amdgcn_ds_bpermute(A1b, (int)lo1);
    unsigned h0 = 0, h1 = 0, h2 = 0, h3 = 0;
    if (HI) {
        h0 = (unsigned)__builtin_amdgcn_ds_bpermute(A0b, (int)hi0);
        h1 = (unsigned)__builtin_amdgcn_ds_bpermute(A0b, (int)hi1);
        h2 = (unsigned)__builtin_amdgcn_ds_bpermute(A1b, (int)hi0);
        h3 = (unsigned)__builtin_amdgcn_ds_bpermute(A1b, (int)hi1);
    }
    return frag_from_words(hiSel ? h0 : l0, hiSel ? h1 : l1,
                           hiSel ? h2 : l2, hiSel ? h3 : l3);
}

// ---------------- prep: transposed bias/mask tables + weight bf16 fragment layouts --------
__global__ void prep_kernel(const float* __restrict__ rpb, const int* __restrict__ relidx,
                            const float* __restrict__ mask,
                            const float* __restrict__ kvw, const float* __restrict__ pw,
                            float* __restrict__ biasT, float* __restrict__ maskT,
                            unsigned short* __restrict__ kvB, unsigned short* __restrict__ pB) {
    int e = blockIdx.x * 256 + threadIdx.x;
    if (e < HEADS * NTOK * NTOK) {
        int h = e / (NTOK * NTOK), rem = e % (NTOK * NTOK);
        int j = rem / NTOK, i = rem % NTOK;
        biasT[e] = rpb[relidx[i * NTOK + j] * HEADS + h];
    }
    if (e < 64 * NTOK * NTOK) {
        int wd = e / (NTOK * NTOK), rem = e % (NTOK * NTOK);
        int j = rem / NTOK, i = rem % NTOK;
        maskT[e] = mask[((size_t)wd * NTOK + i) * NTOK + j];
    }
    if (e < 73728) {
        int jj = e & 7, lane = (e >> 3) & 63, t = e >> 9;
        int NT = t % 24, ks = t / 24;
        int c = ks * 32 + (lane >> 4) * 8 + jj;
        int n = NT * 16 + (lane & 15);
        kvB[e] = f2bf(kvw[c * 384 + n]);
    }
    if (e < 36864) {
        int jj = e & 7, lane = (e >> 3) & 63, t = e >> 9;
        int NT = t % 12, ks = t / 12;
        int c = ks * 32 + (lane >> 4) * 8 + jj;
        int n = NT * 16 + (lane & 15);
        pB[e] = f2bf(pw[c * 192 + n]);
    }
}

// ---------------- attn: swapped-QK, per (window, head-triple); O -> out (f32) -------------
// LDS: kB3 21504 B + vB3 24576 B = 46080.
// __launch_bounds__(448,2): empirically 2nd arg = blocks/CU -> 128-reg cap.
// r5's (448,3) forced an 85-reg cap -> ~12 regs spilled (~45 MB scratch WRITE) AND throttled
// occupancy to 20%. 128-reg cap removes the spill; residency 2 blocks/CU (14 waves).
__global__ __launch_bounds__(448, 2) void attn_kernel(
    const float* __restrict__ skip, const float* __restrict__ xup,
    const float* __restrict__ kv_b,
    const float* __restrict__ biasT, const float* __restrict__ maskT,
    const unsigned short* __restrict__ kvB,
    float* __restrict__ out) {

    __shared__ __align__(16) unsigned short kB3[3 * 7 * 512];
    __shared__ __align__(16) unsigned short vB3[3 * 2 * 4 * 512];

    const int tid  = threadIdx.x;
    const int w    = tid >> 6;        // wave id = i-tile
    const int lane = tid & 63;
    const int l15  = lane & 15;
    const int quad = lane >> 4;
    const int win  = blockIdx.x >> 1;
    const int g    = blockIdx.x & 1;  // head triple: 3g..3g+2

    // zero v pad slab (j tokens 96..127 region; real 96,97 re-written by staging)
    for (int e = tid; e < 6 * 512; e += 448)
        vB3[(e / 512) * 2048 + 3 * 512 + (e & 511)] = 0;
    __syncthreads();

    const int mA  = w * 16 + l15;          // this lane's i (token)
    const int mAc = mA < NTOK ? mA : 97;   // clamp pad rows (finite, discarded)

    const int A0b = ((32 * (quad & 1) + l15) << 2);   // bpermute byte addrs
    const int A1b = A0b + 64;

    // ---- stage k,v for heads 3g..3g+2 ----
    {
        shortx8 afr[6];
        const float* sr = skip + ((size_t)win * NTOK + mAc) * DIM + quad * 8;
        #pragma unroll
        for (int ks = 0; ks < 6; ++ks) afr[ks] = pack8(sr + ks * 32, 1.0f);
        #pragma unroll
        for (int nt = 0; nt < 12; ++nt) {
            const int NTg = (nt < 6) ? (6 * g + nt) : (6 + 6 * g + nt);
            const float cb = kv_b[NTg * 16 + l15];
            floatx4 acc = {cb, cb, cb, cb};
            #pragma unroll
            for (int ks = 0; ks < 6; ++ks) {
                shortx8 bf = *(const shortx8*)(kvB + ((size_t)((ks * 24 + NTg) * 64 + lane)) * 8);
                acc = __builtin_amdgcn_mfma_f32_16x16x32_bf16(afr[ks], bf, acc, 0, 0, 0);
            }
            if (nt < 6) {  // k -> kB3 (A-frag for swapped QK)
                const int ch = nt * 16 + l15, hh = ch >> 5, dh = ch & 31;
                const int base = ((hh * 7 + w) * 64) * 8 + (dh & 7);
                const int lphi = ((dh >> 3) & 3) << 4;
                #pragma unroll
                for (int r = 0; r < 4; ++r) {
                    int mm = quad * 4 + r;   // pad rows written too: finite row-97 copies
                    kB3[base + (mm | lphi) * 8] = f2bf(acc[r]);
                }
            } else {       // v -> vB3 (A-frag for swapped PV)
                const int cv = (nt - 6) * 16 + l15, hh = cv >> 5, dh = cv & 31, ntv = dh >> 4;
                #pragma unroll
                for (int r = 0; r < 4; ++r) {
                    int m = w * 16 + quad * 4 + r;
                    if (m < NTOK) {
                        int lp = (dh & 15) | (((m >> 3) & 3) << 4);
                        vB3[(((hh * 2 + ntv) * 4 + (m >> 5)) * 64 + lp) * 8 + (m & 7)] = f2bf(acc[r]);
                    }
                }
            }
        }
    }
    __syncthreads();   // kB3/vB3 visible — the only barrier pair in the kernel

    // ---- 3 heads: swapped QK + per-lane softmax + PV via quad-exchange ----
    #pragma unroll
    for (int hp = 0; hp < 3; ++hp) {
        const int h = 3 * g + hp;
        shortx8 qf = pack8(xup + ((size_t)win * NTOK + mAc) * DIM + h * 32 + quad * 8, SCALE);

        // C-init: S'[j][i] = bias[h][i][j] + mask[win][i][j] (transposed tables)
        floatx4 S[7];
        {
            const float* bT = biasT + (size_t)h * (NTOK * NTOK);
            const float* mT = maskT + (size_t)(win & 63) * (NTOK * NTOK);
            #pragma unroll
            for (int nt = 0; nt < 7; ++nt) {
                #pragma unroll
                for (int r = 0; r < 4; ++r) {
                    int j = nt * 16 + quad * 4 + r;
                    S[nt][r] = (j < NTOK) ? (bT[j * NTOK + mAc] + mT[j * NTOK + mAc])
                                          : -1e30f;
                }
            }
        }
        // swapped QK: S' = K·Qᵀ (lane: col i=l15, rows j=nt*16+quad*4+r)
        #pragma unroll
        for (int nt = 0; nt < 7; ++nt) {
            shortx8 bk = *(const shortx8*)&kB3[((hp * 7 + nt) * 64 + lane) * 8];
            S[nt] = __builtin_amdgcn_mfma_f32_16x16x32_bf16(bk, qf, S[nt], 0, 0, 0);
        }
        // softmax over row i=l15: 28 in-lane + cross-quad reduce (xor 16, 32)
        float mx;
        {
            float m0 = fmaxf(fmaxf(S[0][0], S[0][1]), fmaxf(S[0][2], S[0][3]));
            float m1 = fmaxf(fmaxf(S[1][0], S[1][1]), fmaxf(S[1][2], S[1][3]));
            float m2 = fmaxf(fmaxf(S[2][0], S[2][1]), fmaxf(S[2][2], S[2][3]));
            float m3 = fmaxf(fmaxf(S[3][0], S[3][1]), fmaxf(S[3][2], S[3][3]));
            float m4 = fmaxf(fmaxf(S[4][0], S[4][1]), fmaxf(S[4][2], S[4][3]));
            float m5 = fmaxf(fmaxf(S[5][0], S[5][1]), fmaxf(S[5][2], S[5][3]));
            float m6 = fmaxf(fmaxf(S[6][0], S[6][1]), fmaxf(S[6][2], S[6][3]));
            mx = fmaxf(fmaxf(fmaxf(m0, m1), fmaxf(m2, m3)), fmaxf(fmaxf(m4, m5), m6));
            mx = fmaxf(mx, __shfl_xor(mx, 16));
            mx = fmaxf(mx, __shfl_xor(mx, 32));
        }
        float sm = 0.f;
        #pragma unroll
        for (int nt = 0; nt < 7; ++nt) {
            #pragma unroll
            for (int r = 0; r < 4; ++r) { S[nt][r] = __expf(S[nt][r] - mx); }
            sm += (S[nt][0] + S[nt][1]) + (S[nt][2] + S[nt][3]);
        }
        sm += __shfl_xor(sm, 16);
        sm += __shfl_xor(sm, 32);
        const float inv = 1.0f / sm;   // per-lane (row i=l15)

        // pack P rows (unnormalized) as bf16 pairs
        unsigned pk[7][2];
        #pragma unroll
        for (int nt = 0; nt < 7; ++nt) {
            pk[nt][0] = (unsigned)f2bf(S[nt][0]) | ((unsigned)f2bf(S[nt][1]) << 16);
            pk[nt][1] = (unsigned)f2bf(S[nt][2]) | ((unsigned)f2bf(S[nt][3]) << 16);
        }
        // PV: O^T[dh][i] += Vᵀ·P' (A=vB3 frag, B=P' via quad-exchange)
        floatx4 o0 = {0.f, 0.f, 0.f, 0.f}, o1 = {0.f, 0.f, 0.f, 0.f};
        const bool hiSel = (quad & 2) != 0;
        #pragma unroll
        for (int ks = 0; ks < 4; ++ks) {
            shortx8 pfr;
            if (ks < 3)
                pfr = xchg4<true>(pk[2 * ks][0], pk[2 * ks][1],
                                  pk[2 * ks + 1][0], pk[2 * ks + 1][1], A0b, A1b, hiSel);
            else
                pfr = xchg4<false>(pk[6][0], pk[6][1], 0u, 0u, A0b, A1b, hiSel);
            shortx8 vb0 = *(const shortx8*)&vB3[(((hp * 2 + 0) * 4 + ks) * 64 + lane) * 8];
            o0 = __builtin_amdgcn_mfma_f32_16x16x32_bf16(vb0, pfr, o0, 0, 0, 0);
            shortx8 vb1 = *(const shortx8*)&vB3[(((hp * 2 + 1) * 4 + ks) * 64 + lane) * 8];
            o1 = __builtin_amdgcn_mfma_f32_16x16x32_bf16(vb1, pfr, o1, 0, 0, 0);
        }
        // O store (normalized f32): lane holds col i=l15, rows dh=quad*4+r per ntv tile
        if (mA < NTOK) {
            float* orow = out + ((size_t)win * NTOK + mA) * DIM + h * 32;
            #pragma unroll
            for (int r = 0; r < 4; ++r) {
                orow[quad * 4 + r]      = o0[r] * inv;
                orow[16 + quad * 4 + r] = o1[r] * inv;
            }
        }
    }
}

// ---------------- proj: in-place out = O @ proj_w + proj_b, one wave per (win, mtile) -----
// grid 3584 x 128; (128,8): 8 blocks/CU -> 16 waves/CU -> 128-reg cap (no spill).
// In-place safe: each wave reads only its own mtile's rows (regs) before storing them.
__global__ __launch_bounds__(128, 8) void proj_kernel(
    float* __restrict__ io, const unsigned short* __restrict__ pB,
    const float* __restrict__ pb) {
    const int tid  = threadIdx.x;
    const int lane = tid & 63;
    const int l15  = lane & 15;
    const int quad = lane >> 4;
    const int idx  = blockIdx.x * 2 + (tid >> 6);   // (win*7 + mt), 0..7167
    const int win  = idx / 7;
    const int mt   = idx - win * 7;

    float* base = io + (size_t)win * NTOK * DIM;
    const int mA  = mt * 16 + l15;
    const int mAc = mA < NTOK ? mA : 97;

    shortx8 afr[6];
    {
        const float* ar = base + mAc * DIM + quad * 8;
        #pragma unroll
        for (int ks = 0; ks < 6; ++ks) afr[ks] = pack8(ar + ks * 32, 1.0f);
    }
    #pragma unroll
    for (int nt = 0; nt < 12; ++nt) {
        const int n = nt * 16 + l15;
        const float bb = pb[n];
        floatx4 acc = {bb, bb, bb, bb};
        #pragma unroll
        for (int ks = 0; ks < 6; ++ks) {
            shortx8 bf = *(const shortx8*)(pB + ((size_t)((ks * 12 + nt) * 64 + lane)) * 8);
            acc = __builtin_amdgcn_mfma_f32_16x16x32_bf16(afr[ks], bf, acc, 0, 0, 0);
        }
        #pragma unroll
        for (int r = 0; r < 4; ++r) {
            int m = mt * 16 + quad * 4 + r;
            if (m < NTOK) base[m * DIM + n] = acc[r];
        }
    }
}

extern "C" void kernel_launch(void* const* d_in, const int* in_sizes, int n_in,
                              void* d_out, int out_size, void* d_ws, size_t ws_size,
                              hipStream_t stream) {
    const float* skip   = (const float*)d_in[0];
    const float* x_up   = (const float*)d_in[1];
    const float* mask   = (const float*)d_in[2];
    const float* kv_w   = (const float*)d_in[3];
    const float* kv_b   = (const float*)d_in[4];
    const float* proj_w = (const float*)d_in[5];
    const float* proj_b = (const float*)d_in[6];
    const float* rpb    = (const float*)d_in[7];
    const int*   relidx = (const int*)d_in[8];
    float* out = (float*)d_out;

    float*          biasT = (float*)d_ws;                                 //   230,496 B
    float*          maskT = (float*)((char*)d_ws + 230496);               // 2,458,624 B
    unsigned short* kvB   = (unsigned short*)((char*)d_ws + 2689120);     //   147,456 B
    unsigned short* pB    = (unsigned short*)((char*)d_ws + 2836576);     //    73,728 B

    prep_kernel<<<2402, 256, 0, stream>>>(rpb, relidx, mask, kv_w, proj_w,
                                          biasT, maskT, kvB, pB);
    attn_kernel<<<2048, 448, 0, stream>>>(skip, x_up, kv_b, biasT, maskT, kvB, out);
    proj_kernel<<<3584, 128, 0, stream>>>(out, pB, proj_b);
}

// Round 8
// 326.137 us; speedup vs baseline: 1.4098x; 1.1108x over previous
//
#include <hip/hip_runtime.h>

#define NTOK 98
#define DIM 192
#define HEADS 6
#define SCALE 0.17677669529663687f

using shortx8 = __attribute__((ext_vector_type(8))) short;
using floatx4 = __attribute__((ext_vector_type(4))) float;

static __device__ __forceinline__ unsigned short f2bf(float f) {
    unsigned u = __float_as_uint(f);
    u += 0x7FFFu + ((u >> 16) & 1u);   // RNE
    return (unsigned short)(u >> 16);
}

static __device__ __forceinline__ shortx8 pack8(const float* p, float scale) {
    float4 a = *(const float4*)p;
    float4 b = *(const float4*)(p + 4);
    shortx8 t;
    t[0] = (short)f2bf(a.x * scale); t[1] = (short)f2bf(a.y * scale);
    t[2] = (short)f2bf(a.z * scale); t[3] = (short)f2bf(a.w * scale);
    t[4] = (short)f2bf(b.x * scale); t[5] = (short)f2bf(b.y * scale);
    t[6] = (short)f2bf(b.z * scale); t[7] = (short)f2bf(b.w * scale);
    return t;
}

static __device__ __forceinline__ shortx8 frag_from_words(unsigned w0, unsigned w1,
                                                          unsigned w2, unsigned w3) {
    union { unsigned u[4]; shortx8 s; } t;
    t.u[0] = w0; t.u[1] = w1; t.u[2] = w2; t.u[3] = w3;
    return t.s;
}

// quad-exchange (validated r4-r6): build frag words from the 4 lanes sharing l15.
template <bool HI>
static __device__ __forceinline__ shortx8 xchg4(unsigned lo0, unsigned lo1,
                                                unsigned hi0, unsigned hi1,
                                                int A0b, int A1b, bool hiSel) {
    unsigned l0 = (unsigned)__builtin_amdgcn_ds_bpermute(A0b, (int)lo0);
    unsigned l1 = (unsigned)__builtin_amdgcn_ds_bpermute(A0b, (int)lo1);
    unsigned l2 = (unsigned)__builtin_amdgcn_ds_bpermute(A1b, (int)lo0);
    unsigned l3 = (unsigned)__builtin_amdgcn_ds_bpermute(A1b, (int)lo1);
    unsigned h0 = 0, h1 = 0, h2 = 0, h3 = 0;
    if (HI) {
        h0 = (unsigned)__builtin_amdgcn_ds_bpermute(A0b, (int)hi0);
        h1 = (unsigned)__builtin_amdgcn_ds_bpermute(A0b, (int)hi1);
        h2 = (unsigned)__builtin_amdgcn_ds_bpermute(A1b, (int)hi0);
        h3 = (unsigned)__builtin_amdgcn_ds_bpermute(A1b, (int)hi1);
    }
    return frag_from_words(hiSel ? h0 : l0, hiSel ? h1 : l1,
                           hiSel ? h2 : l2, hiSel ? h3 : l3);
}

// ---------------- prep: padded add-ready bias/mask tables + weight bf16 frag layouts ------
// biasP[h][i][j112] = bias[h][i][j] (j>=98 -> -1e30)   (112-float rows => float4-aligned)
// maskP[w][i][j112] = mask[w][i][j] (j>=98 -> 0)
// kvB[((ks*24+NT)*64+lane)*8+jj] = kv_w[(ks*32+quad*8+jj)*384 + NT*16+(lane&15)]
// pB [((ks*12+NT)*64+lane)*8+jj] = proj_w[(ks*32+quad*8+jj)*192 + NT*16+(lane&15)]
__global__ void prep_kernel(const float* __restrict__ rpb, const int* __restrict__ relidx,
                            const float* __restrict__ mask,
                            const float* __restrict__ kvw, const float* __restrict__ pw,
                            float* __restrict__ biasP, float* __restrict__ maskP,
                            unsigned short* __restrict__ kvB, unsigned short* __restrict__ pB) {
    int e = blockIdx.x * 256 + threadIdx.x;
    if (e < HEADS * NTOK * 112) {
        int h = e / (NTOK * 112), rem = e % (NTOK * 112);
        int i = rem / 112, j = rem % 112;
        biasP[e] = (j < NTOK) ? rpb[relidx[i * NTOK + j] * HEADS + h] : -1e30f;
    }
    if (e < 64 * NTOK * 112) {
        int wd = e / (NTOK * 112), rem = e % (NTOK * 112);
        int i = rem / 112, j = rem % 112;
        maskP[e] = (j < NTOK) ? mask[((size_t)wd * NTOK + i) * NTOK + j] : 0.f;
    }
    if (e < 73728) {
        int jj = e & 7, lane = (e >> 3) & 63, t = e >> 9;
        int NT = t % 24, ks = t / 24;
        int c = ks * 32 + (lane >> 4) * 8 + jj;
        int n = NT * 16 + (lane & 15);
        kvB[e] = f2bf(kvw[c * 384 + n]);
    }
    if (e < 36864) {
        int jj = e & 7, lane = (e >> 3) & 63, t = e >> 9;
        int NT = t % 12, ks = t / 12;
        int c = ks * 32 + (lane >> 4) * 8 + jj;
        int n = NT * 16 + (lane & 15);
        pB[e] = f2bf(pw[c * 192 + n]);
    }
}

// ---------------- attn: swapped-QK, per (window, head-triple); O -> bf16 proj-A-frags -----
// O frags stored into the FRONT of out's own window region (slab mt at byte win*75264 +
// mt*6144, h*1024 + lane*16 within slab) -> coalesced 16B/lane stores, no extra ws.
// LDS 46080 B; (448,2) -> 128-reg cap (r6: natural 92, no spill), 2 blocks/CU.
__global__ __launch_bounds__(448, 2) void attn_kernel(
    const float* __restrict__ skip, const float* __restrict__ xup,
    const float* __restrict__ kv_b,
    const float* __restrict__ biasP, const float* __restrict__ maskP,
    const unsigned short* __restrict__ kvB,
    unsigned short* __restrict__ outS) {

    __shared__ __align__(16) unsigned short kB3[3 * 7 * 512];
    __shared__ __align__(16) unsigned short vB3[3 * 2 * 4 * 512];

    const int tid  = threadIdx.x;
    const int w    = tid >> 6;        // wave id = i-tile
    const int lane = tid & 63;
    const int l15  = lane & 15;
    const int quad = lane >> 4;
    const int win  = blockIdx.x >> 1;
    const int g    = blockIdx.x & 1;  // head triple: 3g..3g+2

    // zero v pad slab (j tokens 96..127 region; real 96,97 re-written by staging)
    for (int e = tid; e < 6 * 512; e += 448)
        vB3[(e / 512) * 2048 + 3 * 512 + (e & 511)] = 0;
    __syncthreads();

    const int mA  = w * 16 + l15;          // this lane's i (token)
    const int mAc = mA < NTOK ? mA : 97;   // clamp pad rows (finite, discarded by proj)

    const int A0b = ((32 * (quad & 1) + l15) << 2);   // bpermute byte addrs
    const int A1b = A0b + 64;

    // ---- stage k,v for heads 3g..3g+2 ----
    {
        shortx8 afr[6];
        const float* sr = skip + ((size_t)win * NTOK + mAc) * DIM + quad * 8;
        #pragma unroll
        for (int ks = 0; ks < 6; ++ks) afr[ks] = pack8(sr + ks * 32, 1.0f);
        #pragma unroll
        for (int nt = 0; nt < 12; ++nt) {
            const int NTg = (nt < 6) ? (6 * g + nt) : (6 + 6 * g + nt);
            const float cb = kv_b[NTg * 16 + l15];
            floatx4 acc = {cb, cb, cb, cb};
            #pragma unroll
            for (int ks = 0; ks < 6; ++ks) {
                shortx8 bf = *(const shortx8*)(kvB + ((size_t)((ks * 24 + NTg) * 64 + lane)) * 8);
                acc = __builtin_amdgcn_mfma_f32_16x16x32_bf16(afr[ks], bf, acc, 0, 0, 0);
            }
            if (nt < 6) {  // k -> kB3 (A-frag for swapped QK)
                const int ch = nt * 16 + l15, hh = ch >> 5, dh = ch & 31;
                const int base = ((hh * 7 + w) * 64) * 8 + (dh & 7);
                const int lphi = ((dh >> 3) & 3) << 4;
                #pragma unroll
                for (int r = 0; r < 4; ++r) {
                    int mm = quad * 4 + r;   // pad rows written too: finite row-97 copies
                    kB3[base + (mm | lphi) * 8] = f2bf(acc[r]);
                }
            } else {       // v -> vB3 (A-frag for swapped PV)
                const int cv = (nt - 6) * 16 + l15, hh = cv >> 5, dh = cv & 31, ntv = dh >> 4;
                #pragma unroll
                for (int r = 0; r < 4; ++r) {
                    int m = w * 16 + quad * 4 + r;
                    if (m < NTOK) {
                        int lp = (dh & 15) | (((m >> 3) & 3) << 4);
                        vB3[(((hh * 2 + ntv) * 4 + (m >> 5)) * 64 + lp) * 8 + (m & 7)] = f2bf(acc[r]);
                    }
                }
            }
        }
    }
    __syncthreads();   // kB3/vB3 visible — the only barrier pair in the kernel

    // ---- 3 heads: swapped QK + per-lane softmax + PV via quad-exchange ----
    #pragma unroll
    for (int hp = 0; hp < 3; ++hp) {
        const int h = 3 * g + hp;
        shortx8 qf = pack8(xup + ((size_t)win * NTOK + mAc) * DIM + h * 32 + quad * 8, SCALE);

        // C-init: S'[j][i] = biasP[h][i][j] + maskP[win][i][j], float4 loads (pad built-in)
        floatx4 S[7];
        {
            const float* bp = biasP + ((size_t)h * NTOK + mAc) * 112;
            const float* mp = maskP + ((size_t)(win & 63) * NTOK + mAc) * 112;
            #pragma unroll
            for (int nt = 0; nt < 7; ++nt) {
                float4 b4 = *(const float4*)(bp + nt * 16 + quad * 4);
                float4 m4 = *(const float4*)(mp + nt * 16 + quad * 4);
                S[nt][0] = b4.x + m4.x; S[nt][1] = b4.y + m4.y;
                S[nt][2] = b4.z + m4.z; S[nt][3] = b4.w + m4.w;
            }
        }
        // swapped QK: S' = K·Qᵀ (lane: col i=l15, rows j=nt*16+quad*4+r)
        #pragma unroll
        for (int nt = 0; nt < 7; ++nt) {
            shortx8 bk = *(const shortx8*)&kB3[((hp * 7 + nt) * 64 + lane) * 8];
            S[nt] = __builtin_amdgcn_mfma_f32_16x16x32_bf16(bk, qf, S[nt], 0, 0, 0);
        }
        // softmax over row i=l15: 28 in-lane + cross-quad reduce (xor 16, 32)
        float mx;
        {
            float m0 = fmaxf(fmaxf(S[0][0], S[0][1]), fmaxf(S[0][2], S[0][3]));
            float m1 = fmaxf(fmaxf(S[1][0], S[1][1]), fmaxf(S[1][2], S[1][3]));
            float m2 = fmaxf(fmaxf(S[2][0], S[2][1]), fmaxf(S[2][2], S[2][3]));
            float m3 = fmaxf(fmaxf(S[3][0], S[3][1]), fmaxf(S[3][2], S[3][3]));
            float m4 = fmaxf(fmaxf(S[4][0], S[4][1]), fmaxf(S[4][2], S[4][3]));
            float m5 = fmaxf(fmaxf(S[5][0], S[5][1]), fmaxf(S[5][2], S[5][3]));
            float m6 = fmaxf(fmaxf(S[6][0], S[6][1]), fmaxf(S[6][2], S[6][3]));
            mx = fmaxf(fmaxf(fmaxf(m0, m1), fmaxf(m2, m3)), fmaxf(fmaxf(m4, m5), m6));
            mx = fmaxf(mx, __shfl_xor(mx, 16));
            mx = fmaxf(mx, __shfl_xor(mx, 32));
        }
        float sm = 0.f;
        #pragma unroll
        for (int nt = 0; nt < 7; ++nt) {
            #pragma unroll
            for (int r = 0; r < 4; ++r) { S[nt][r] = __expf(S[nt][r] - mx); }
            sm += (S[nt][0] + S[nt][1]) + (S[nt][2] + S[nt][3]);
        }
        sm += __shfl_xor(sm, 16);
        sm += __shfl_xor(sm, 32);
        const float inv = 1.0f / sm;   // per-lane (row i=l15)

        // pack P rows (unnormalized) as bf16 pairs
        unsigned pk[7][2];
        #pragma unroll
        for (int nt = 0; nt < 7; ++nt) {
            pk[nt][0] = (unsigned)f2bf(S[nt][0]) | ((unsigned)f2bf(S[nt][1]) << 16);
            pk[nt][1] = (unsigned)f2bf(S[nt][2]) | ((unsigned)f2bf(S[nt][3]) << 16);
        }
        // PV: O^T[dh][i] += Vᵀ·P' (A=vB3 frag, B=P' via quad-exchange)
        floatx4 o0 = {0.f, 0.f, 0.f, 0.f}, o1 = {0.f, 0.f, 0.f, 0.f};
        const bool hiSel = (quad & 2) != 0;
        #pragma unroll
        for (int ks = 0; ks < 4; ++ks) {
            shortx8 pfr;
            if (ks < 3)
                pfr = xchg4<true>(pk[2 * ks][0], pk[2 * ks][1],
                                  pk[2 * ks + 1][0], pk[2 * ks + 1][1], A0b, A1b, hiSel);
            else
                pfr = xchg4<false>(pk[6][0], pk[6][1], 0u, 0u, A0b, A1b, hiSel);
            shortx8 vb0 = *(const shortx8*)&vB3[(((hp * 2 + 0) * 4 + ks) * 64 + lane) * 8];
            o0 = __builtin_amdgcn_mfma_f32_16x16x32_bf16(vb0, pfr, o0, 0, 0, 0);
            shortx8 vb1 = *(const shortx8*)&vB3[(((hp * 2 + 1) * 4 + ks) * 64 + lane) * 8];
            o1 = __builtin_amdgcn_mfma_f32_16x16x32_bf16(vb1, pfr, o1, 0, 0, 0);
        }
        // normalize, pack, transpose to proj A-frag via xchg4 (r4-validated), 16B store
        unsigned w0 = (unsigned)f2bf(o0[0] * inv) | ((unsigned)f2bf(o0[1] * inv) << 16);
        unsigned w1 = (unsigned)f2bf(o0[2] * inv) | ((unsigned)f2bf(o0[3] * inv) << 16);
        unsigned w2 = (unsigned)f2bf(o1[0] * inv) | ((unsigned)f2bf(o1[1] * inv) << 16);
        unsigned w3 = (unsigned)f2bf(o1[2] * inv) | ((unsigned)f2bf(o1[3] * inv) << 16);
        shortx8 oa = xchg4<true>(w0, w1, w2, w3, A0b, A1b, hiSel);
        // slab for (win, mt=w): shorts offset win*37632 + w*3072 + h*512 + lane*8
        *(shortx8*)(outS + (size_t)win * 37632 + w * 3072 + h * 512 + lane * 8) = oa;
    }
}

// ---------------- proj: out = Ofrag @ proj_w + proj_b, in-place over the frag slabs -------
// One block per window (1024 x 448). Wave w reads its own slab (6 A-frags, 16B/lane loads),
// one barrier (row-writes of wave w clobber slabs 2w,2w+1), then 72 MFMAs + coalesced rows.
__global__ __launch_bounds__(448, 4) void proj_kernel(
    float* __restrict__ io, const unsigned short* __restrict__ pB,
    const float* __restrict__ pb) {
    const int tid  = threadIdx.x;
    const int w    = tid >> 6;
    const int lane = tid & 63;
    const int l15  = lane & 15;
    const int quad = lane >> 4;
    const int win  = blockIdx.x;

    const unsigned short* slab = (const unsigned short*)io + (size_t)win * 37632 + w * 3072;
    shortx8 afr[6];
    #pragma unroll
    for (int ks = 0; ks < 6; ++ks)
        afr[ks] = *(const shortx8*)(slab + ks * 512 + lane * 8);
    __syncthreads();   // all slab reads done before any row writes

    float* base = io + (size_t)win * NTOK * DIM;
    #pragma unroll
    for (int nt = 0; nt < 12; ++nt) {
        const int n = nt * 16 + l15;
        const float bb = pb[n];
        floatx4 acc = {bb, bb, bb, bb};
        #pragma unroll
        for (int ks = 0; ks < 6; ++ks) {
            shortx8 bf = *(const shortx8*)(pB + ((size_t)((ks * 12 + nt) * 64 + lane)) * 8);
            acc = __builtin_amdgcn_mfma_f32_16x16x32_bf16(afr[ks], bf, acc, 0, 0, 0);
        }
        #pragma unroll
        for (int r = 0; r < 4; ++r) {
            int m = w * 16 + quad * 4 + r;
            if (m < NTOK) base[m * DIM + n] = acc[r];
        }
    }
}

extern "C" void kernel_launch(void* const* d_in, const int* in_sizes, int n_in,
                              void* d_out, int out_size, void* d_ws, size_t ws_size,
                              hipStream_t stream) {
    const float* skip   = (const float*)d_in[0];
    const float* x_up   = (const float*)d_in[1];
    const float* mask   = (const float*)d_in[2];
    const float* kv_w   = (const float*)d_in[3];
    const float* kv_b   = (const float*)d_in[4];
    const float* proj_w = (const float*)d_in[5];
    const float* proj_b = (const float*)d_in[6];
    const float* rpb    = (const float*)d_in[7];
    const int*   relidx = (const int*)d_in[8];
    float* out = (float*)d_out;

    float*          biasP = (float*)d_ws;                                 //   263,424 B
    float*          maskP = (float*)((char*)d_ws + 263424);               // 2,809,856 B
    unsigned short* kvB   = (unsigned short*)((char*)d_ws + 3073280);     //   147,456 B
    unsigned short* pB    = (unsigned short*)((char*)d_ws + 3220736);     //    73,728 B

    prep_kernel<<<2744, 256, 0, stream>>>(rpb, relidx, mask, kv_w, proj_w,
                                          biasP, maskP, kvB, pB);
    attn_kernel<<<2048, 448, 0, stream>>>(skip, x_up, kv_b, biasP, maskP, kvB,
                                          (unsigned short*)out);
    proj_kernel<<<1024, 448, 0, stream>>>(out, pB, proj_b);
}